// Round 3
// baseline (340.288 us; speedup 1.0000x reference)
//
#include <hip/hip_runtime.h>
#include <stdint.h>

// VoxelLayer: JAX voxel-grid downsample ×2, bit-exact Threefry-2x32
// (partitionable) sampling. Round 3: ILP min, partial-store accum (no global
// atomics when ws allows), ballot-scan compact, fused min2-into-sample1,
// 4-wide float4 sample.

typedef unsigned int u32;
typedef unsigned long long u64;

struct KeyArr { uint32_t k0[16]; uint32_t k1[16]; };

__host__ __device__ inline void tf2x32(uint32_t k0, uint32_t k1,
                                       uint32_t c0, uint32_t c1,
                                       uint32_t& o0, uint32_t& o1) {
  const uint32_t ks0 = k0, ks1 = k1, ks2 = k0 ^ k1 ^ 0x1BD11BDAu;
  uint32_t x0 = c0 + ks0, x1 = c1 + ks1;
#define TF_R(r) { x0 += x1; x1 = (x1 << (r)) | (x1 >> (32 - (r))); x1 ^= x0; }
  TF_R(13) TF_R(15) TF_R(26) TF_R(6)
  x0 += ks1; x1 += ks2 + 1u;
  TF_R(17) TF_R(29) TF_R(16) TF_R(24)
  x0 += ks2; x1 += ks0 + 2u;
  TF_R(13) TF_R(15) TF_R(26) TF_R(6)
  x0 += ks0; x1 += ks1 + 3u;
  TF_R(17) TF_R(29) TF_R(16) TF_R(24)
  x0 += ks1; x1 += ks2 + 4u;
  TF_R(13) TF_R(15) TF_R(26) TF_R(6)
  x0 += ks2; x1 += ks0 + 5u;
#undef TF_R
  o0 = x0; o1 = x1;
}

// ---- init: zero cells (atomic path only), min=+inf, numvox=0 ----
__global__ void init_kernel(u64* cellsA, u64* cellsB, int ncells,
                            u32* mnbits, u32* numvox) {
  int i = blockIdx.x * blockDim.x + threadIdx.x;
  int stride = gridDim.x * blockDim.x;
  for (int j = i; j < ncells; j += stride) { cellsA[j] = 0ull; cellsB[j] = 0ull; }
  if (i < 96) mnbits[i] = 0x7F800000u;  // +inf
  if (i < 32) numvox[i] = 0u;
}

// ---- per-(batch,coord) min: 4 independent float4 loads/thread ----
__global__ void min_kernel(const float* __restrict__ in, int n4,
                           u32* __restrict__ mnb) {
  int row = blockIdx.y;  // b*3+c in [0,48)
  const float4* p = (const float4*)in + (size_t)row * n4;
  int base = blockIdx.x * 1024 + threadIdx.x;
  float4 a = p[base];
  float4 b = p[base + 256];
  float4 c = p[base + 512];
  float4 d = p[base + 768];
  float m0 = fminf(fminf(a.x, a.y), fminf(a.z, a.w));
  float m1 = fminf(fminf(b.x, b.y), fminf(b.z, b.w));
  float m2 = fminf(fminf(c.x, c.y), fminf(c.z, c.w));
  float m3 = fminf(fminf(d.x, d.y), fminf(d.z, d.w));
  float m = fminf(fminf(m0, m1), fminf(m2, m3));
  for (int off = 32; off > 0; off >>= 1)
    m = fminf(m, __shfl_down(m, off, 64));
  if ((threadIdx.x & 63) == 0)
    atomicMin((int*)&mnb[row], __float_as_int(m));  // values >= 0
}

// ---- LDS-privatized accumulation; merge = plain store (partial) or atomic ----
template <int G, int S, bool ATOMIC>
__global__ __launch_bounds__(1024) void accum_kernel(
    const float* __restrict__ in, int N, float vox,
    const u32* __restrict__ mnb, u64* __restrict__ Ap, u64* __restrict__ Bp) {
  extern __shared__ u64 lds[];
  u64* lA = lds;      // [G]  A = (ysum<<32)|xsum   (Q20)
  u64* lB = lds + G;  // [G]  B = (cnt <<32)|zsum
  int tid = threadIdx.x, b = blockIdx.y;
  for (int i = tid; i < G; i += 1024) { lA[i] = 0ull; lB[i] = 0ull; }
  __syncthreads();

  float m0 = __uint_as_float(mnb[b * 3 + 0]);
  float m1 = __uint_as_float(mnb[b * 3 + 1]);
  float m2 = __uint_as_float(mnb[b * 3 + 2]);
  int ppb = N / gridDim.x;
  const float* base = in + (size_t)b * 3 * N;
  int start = blockIdx.x * ppb;
  const float4* r0 = (const float4*)(base + start);
  const float4* r1 = (const float4*)(base + N + start);
  const float4* r2 = (const float4*)(base + 2 * N + start);
  int q4 = ppb >> 2;
  for (int i = tid; i < q4; i += 1024) {
    float4 X = r0[i], Y = r1[i], Z = r2[i];
#define PT(px, py, pz) { \
    int v0 = (int)floorf(((px) - m0) / vox); \
    int v1 = (int)floorf(((py) - m1) / vox); \
    int v2 = (int)floorf(((pz) - m2) / vox); \
    int lin = (v0 * S + v1) * S + v2; \
    u32 qx = (u32)((px) * 1048576.0f); \
    u32 qy = (u32)((py) * 1048576.0f); \
    u32 qz = (u32)((pz) * 1048576.0f); \
    atomicAdd(&lA[lin], ((u64)qy << 32) | (u64)qx); \
    atomicAdd(&lB[lin], (1ull << 32) | (u64)qz); }
    PT(X.x, Y.x, Z.x) PT(X.y, Y.y, Z.y) PT(X.z, Y.z, Z.z) PT(X.w, Y.w, Z.w)
#undef PT
  }
  __syncthreads();

  int p = ATOMIC ? 0 : blockIdx.x;
  u64* gA = Ap + ((size_t)p * 16 + b) * G;
  u64* gB = Bp + ((size_t)p * 16 + b) * G;
  for (int c = tid; c < G; c += 1024) {
    if (ATOMIC) {
      u64 Bv = lB[c];
      if (Bv) { atomicAdd(&gA[c], lA[c]); atomicAdd(&gB[c], Bv); }
    } else {
      gA[c] = lA[c];
      gB[c] = lB[c];
    }
  }
}

// ---- sum P partial slices -> per-cell float4 {mx,my,mz,cnt} ----
__global__ void reduce_kernel(int G, int P, const u64* __restrict__ Ap,
                              const u64* __restrict__ Bp,
                              float4* __restrict__ vox4) {
  int cell = blockIdx.x * 256 + threadIdx.x;
  int b = blockIdx.y;
  if (cell >= G) return;
  u64 A = 0ull, Bv = 0ull;
  for (int p = 0; p < P; ++p) {
    size_t o = ((size_t)p * 16 + b) * G + cell;
    A += Ap[o];
    Bv += Bp[o];
  }
  u32 cnt = (u32)(Bv >> 32);
  float4 o4 = make_float4(0.f, 0.f, 0.f, 0.f);
  if (cnt) {
    double inv = 1.0 / (1048576.0 * (double)cnt);
    o4.x = (float)((double)(u32)A * inv);
    o4.y = (float)((double)(u32)(A >> 32) * inv);
    o4.z = (float)((double)(u32)Bv * inv);
    o4.w = (float)cnt;
  }
  vox4[(size_t)b * G + cell] = o4;
}

// ---- ballot-scan compaction (ascending cell = JAX segment order) ----
template <bool FROMVOX>
__global__ __launch_bounds__(1024) void compact_kernel(
    int G, const float4* __restrict__ vox4, const u64* __restrict__ Ac,
    const u64* __restrict__ Bc, float4* __restrict__ means4,
    u32* __restrict__ numvox) {
  int b = blockIdx.x, tid = threadIdx.x, wid = tid >> 6, lane = tid & 63;
  __shared__ u32 wtot[16], wbase[16];
  __shared__ u32 gbase;
  if (tid == 0) gbase = 0u;
  __syncthreads();
  for (int t0 = 0; t0 < G; t0 += 1024) {
    int cell = t0 + tid;
    float4 v = make_float4(0.f, 0.f, 0.f, 0.f);
    u32 cnt = 0u;
    if (cell < G) {
      if (FROMVOX) {
        v = vox4[(size_t)b * G + cell];
        cnt = (u32)v.w;
      } else {
        u64 A = Ac[(size_t)b * G + cell], Bv = Bc[(size_t)b * G + cell];
        cnt = (u32)(Bv >> 32);
        if (cnt) {
          double inv = 1.0 / (1048576.0 * (double)cnt);
          v.x = (float)((double)(u32)A * inv);
          v.y = (float)((double)(u32)(A >> 32) * inv);
          v.z = (float)((double)(u32)Bv * inv);
        }
      }
    }
    bool occ = cnt > 0u;
    u64 mask = __ballot(occ);
    u32 prefix = (u32)__popcll(mask & ((1ull << lane) - 1ull));
    if (lane == 0) wtot[wid] = (u32)__popcll(mask);
    __syncthreads();
    if (tid == 0) {
      u32 s = gbase;
      for (int w = 0; w < 16; ++w) { wbase[w] = s; s += wtot[w]; }
      gbase = s;
    }
    __syncthreads();
    if (occ) means4[(size_t)b * G + wbase[wid] + prefix] = v;
    __syncthreads();
  }
  if (tid == 0) numvox[b] = gbase;
}

// ---- 4-wide threefry sample + optional fused next-layer min ----
template <bool DOMIN>
__global__ void sample_kernel(int L, int G, const float4* __restrict__ means4,
                              const u32* __restrict__ numvox, KeyArr keys,
                              float* __restrict__ out, u32* __restrict__ mnb2) {
  int t = blockIdx.x * blockDim.x + threadIdx.x;
  int b = blockIdx.y;
  int l0 = t * 4;  // L is a multiple of 4*blockDim*gridDim.x -> no guard
  u32 nv = numvox[b];
  float fnv = (float)nv;
  int nvm1 = (int)nv - 1;
  uint32_t K0 = keys.k0[b], K1 = keys.k1[b];
  float4 m[4];
#pragma unroll
  for (int j = 0; j < 4; ++j) {
    uint32_t w0, w1;
    tf2x32(K0, K1, 0u, (uint32_t)(l0 + j), w0, w1);
    uint32_t bits = w0 ^ w1;  // partitionable fold
    float u = __uint_as_float((bits >> 9) | 0x3F800000u) - 1.0f;
    int idx = (int)(u * fnv);  // f32 RN mul, trunc
    if (idx > nvm1) idx = nvm1;
    m[j] = means4[(size_t)b * G + idx];
  }
  *(float4*)(out + ((size_t)b * 3 + 0) * L + l0) =
      make_float4(m[0].x, m[1].x, m[2].x, m[3].x);
  *(float4*)(out + ((size_t)b * 3 + 1) * L + l0) =
      make_float4(m[0].y, m[1].y, m[2].y, m[3].y);
  *(float4*)(out + ((size_t)b * 3 + 2) * L + l0) =
      make_float4(m[0].z, m[1].z, m[2].z, m[3].z);
  if (DOMIN) {
    float ax = fminf(fminf(m[0].x, m[1].x), fminf(m[2].x, m[3].x));
    float ay = fminf(fminf(m[0].y, m[1].y), fminf(m[2].y, m[3].y));
    float az = fminf(fminf(m[0].z, m[1].z), fminf(m[2].z, m[3].z));
    for (int off = 32; off > 0; off >>= 1) {
      ax = fminf(ax, __shfl_down(ax, off, 64));
      ay = fminf(ay, __shfl_down(ay, off, 64));
      az = fminf(az, __shfl_down(az, off, 64));
    }
    if ((threadIdx.x & 63) == 0) {
      atomicMin((int*)&mnb2[b * 3 + 0], __float_as_int(ax));
      atomicMin((int*)&mnb2[b * 3 + 1], __float_as_int(ay));
      atomicMin((int*)&mnb2[b * 3 + 2], __float_as_int(az));
    }
  }
}

extern "C" void kernel_launch(void* const* d_in, const int* in_sizes, int n_in,
                              void* d_out, int out_size, void* d_ws,
                              size_t ws_size, hipStream_t stream) {
  const float* x = (const float*)d_in[0];
  float* out = (float*)d_out;

  // ---- JAX key derivation (threefry partitionable split) ----
  uint32_t k1a, k1b, k2a, k2b;
  tf2x32(0u, 42u, 0u, 0u, k1a, k1b);
  tf2x32(0u, 42u, 0u, 1u, k2a, k2b);
  KeyArr keys1, keys2;
  for (int b = 0; b < 16; ++b) {
    tf2x32(k1a, k1b, 0u, (uint32_t)b, keys1.k0[b], keys1.k1[b]);
    tf2x32(k2a, k2b, 0u, (uint32_t)b, keys2.k0[b], keys2.k1[b]);
  }

  const int N1 = 262144, L1 = 131072, L2 = 65536, G1 = 8000, G2 = 1000;
  const size_t slice1 = (size_t)16 * G1, slice2 = (size_t)16 * G2;

  // big path: 16 partial slices (no global atomics) + vox4 + means4
  const size_t bigNeed = 2ull * 16 * slice1 * 8 + 2ull * slice1 * 16 + 4096;
  bool big = ws_size >= bigNeed;

  uint8_t* w = (uint8_t*)d_ws;
  u64 *Ap, *Bp;
  float4 *vox4 = nullptr, *means4;
  u32 *mnbits, *numvox;
  if (big) {
    Ap = (u64*)w;
    Bp = Ap + 16 * slice1;
    vox4 = (float4*)(Bp + 16 * slice1);
    means4 = vox4 + slice1;
    mnbits = (u32*)(means4 + slice1);
  } else {
    Ap = (u64*)w;                    // [slice1 | slice2] atomic cells
    Bp = Ap + (slice1 + slice2);
    means4 = (float4*)(Bp + (slice1 + slice2));
    mnbits = (u32*)(means4 + slice1);
  }
  numvox = mnbits + 96;

  int ncellsz = big ? 0 : (int)(slice1 + slice2);
  init_kernel<<<dim3(96), dim3(256), 0, stream>>>(Ap, Bp, ncellsz, mnbits,
                                                  numvox);

  // ---- layer 1: vox=0.05, S=20 (v<=19 proven), G=8000 ----
  min_kernel<<<dim3(64, 48), dim3(256), 0, stream>>>(x, N1 / 4, mnbits);
  if (big) {
    accum_kernel<G1, 20, false>
        <<<dim3(16, 16), dim3(1024), 2 * G1 * 8, stream>>>(x, N1, 0.05f,
                                                           mnbits, Ap, Bp);
    reduce_kernel<<<dim3((G1 + 255) / 256, 16), dim3(256), 0, stream>>>(
        G1, 16, Ap, Bp, vox4);
    compact_kernel<true><<<dim3(16), dim3(1024), 0, stream>>>(
        G1, vox4, nullptr, nullptr, means4, numvox);
  } else {
    accum_kernel<G1, 20, true>
        <<<dim3(8, 16), dim3(1024), 2 * G1 * 8, stream>>>(x, N1, 0.05f,
                                                          mnbits, Ap, Bp);
    compact_kernel<false><<<dim3(16), dim3(1024), 0, stream>>>(
        G1, nullptr, Ap, Bp, means4, numvox);
  }
  // sample layer 1 + fused min for layer 2 (out1 min == min of sampled means)
  sample_kernel<true><<<dim3(L1 / 1024, 16), dim3(256), 0, stream>>>(
      L1, G1, means4, numvox, keys1, out, mnbits + 48);

  // ---- layer 2: input = out1, vox=0.1, S=10 (v<=9), G=1000 ----
  float* out2 = out + (size_t)48 * L1;
  if (big) {
    accum_kernel<G2, 10, false>
        <<<dim3(16, 16), dim3(1024), 2 * G2 * 8, stream>>>(out, L1, 0.1f,
                                                           mnbits + 48, Ap, Bp);
    reduce_kernel<<<dim3((G2 + 255) / 256, 16), dim3(256), 0, stream>>>(
        G2, 16, Ap, Bp, vox4);
    compact_kernel<true><<<dim3(16), dim3(1024), 0, stream>>>(
        G2, vox4, nullptr, nullptr, means4, numvox + 16);
  } else {
    accum_kernel<G2, 10, true>
        <<<dim3(8, 16), dim3(1024), 2 * G2 * 8, stream>>>(
            out, L1, 0.1f, mnbits + 48, Ap + slice1, Bp + slice1);
    compact_kernel<false><<<dim3(16), dim3(1024), 0, stream>>>(
        G2, nullptr, Ap + slice1, Bp + slice1, means4, numvox + 16);
  }
  sample_kernel<false><<<dim3(L2 / 1024, 16), dim3(256), 0, stream>>>(
      L2, G2, means4, numvox + 16, keys2, out2, nullptr);
}

// Round 4
// 111.514 us; speedup vs baseline: 3.0515x; 3.0515x over previous
//
#include <hip/hip_runtime.h>
#include <stdint.h>

// VoxelLayer: JAX voxel-grid downsample ×2, bit-exact Threefry-2x32
// (partitionable) sampling. Round 4: un-fuse min from sample (round-3's
// contended atomicMin tail = 184us stall), per-block-atomic ILP min kernel,
// round-2-shape sample with float4 gather.

typedef unsigned int u32;
typedef unsigned long long u64;

struct KeyArr { uint32_t k0[16]; uint32_t k1[16]; };

__host__ __device__ inline void tf2x32(uint32_t k0, uint32_t k1,
                                       uint32_t c0, uint32_t c1,
                                       uint32_t& o0, uint32_t& o1) {
  const uint32_t ks0 = k0, ks1 = k1, ks2 = k0 ^ k1 ^ 0x1BD11BDAu;
  uint32_t x0 = c0 + ks0, x1 = c1 + ks1;
#define TF_R(r) { x0 += x1; x1 = (x1 << (r)) | (x1 >> (32 - (r))); x1 ^= x0; }
  TF_R(13) TF_R(15) TF_R(26) TF_R(6)
  x0 += ks1; x1 += ks2 + 1u;
  TF_R(17) TF_R(29) TF_R(16) TF_R(24)
  x0 += ks2; x1 += ks0 + 2u;
  TF_R(13) TF_R(15) TF_R(26) TF_R(6)
  x0 += ks0; x1 += ks1 + 3u;
  TF_R(17) TF_R(29) TF_R(16) TF_R(24)
  x0 += ks1; x1 += ks2 + 4u;
  TF_R(13) TF_R(15) TF_R(26) TF_R(6)
  x0 += ks2; x1 += ks0 + 5u;
#undef TF_R
  o0 = x0; o1 = x1;
}

// ---- init: zero cells (atomic path only), min=+inf, numvox=0 ----
__global__ void init_kernel(u64* cellsA, u64* cellsB, int ncells,
                            u32* mnbits, u32* numvox) {
  int i = blockIdx.x * blockDim.x + threadIdx.x;
  int stride = gridDim.x * blockDim.x;
  for (int j = i; j < ncells; j += stride) { cellsA[j] = 0ull; cellsB[j] = 0ull; }
  if (i < 96) mnbits[i] = 0x7F800000u;  // +inf
  if (i < 32) numvox[i] = 0u;
}

// ---- per-(batch,coord) min: ILP-4 float4 loads, block-reduce, 1 atomic ----
__global__ void min_kernel(const float* __restrict__ in, int n4,
                           u32* __restrict__ mnb) {
  int row = blockIdx.y;  // b*3+c in [0,48)
  const float4* p = (const float4*)in + (size_t)row * n4;
  int base = blockIdx.x * 1024 + threadIdx.x;
  float4 a = p[base];
  float4 b = p[base + 256];
  float4 c = p[base + 512];
  float4 d = p[base + 768];
  float m0 = fminf(fminf(a.x, a.y), fminf(a.z, a.w));
  float m1 = fminf(fminf(b.x, b.y), fminf(b.z, b.w));
  float m2 = fminf(fminf(c.x, c.y), fminf(c.z, c.w));
  float m3 = fminf(fminf(d.x, d.y), fminf(d.z, d.w));
  float m = fminf(fminf(m0, m1), fminf(m2, m3));
  for (int off = 32; off > 0; off >>= 1)
    m = fminf(m, __shfl_down(m, off, 64));
  __shared__ float wmin[4];
  int wid = threadIdx.x >> 6;
  if ((threadIdx.x & 63) == 0) wmin[wid] = m;
  __syncthreads();
  if (threadIdx.x == 0) {
    float mm = fminf(fminf(wmin[0], wmin[1]), fminf(wmin[2], wmin[3]));
    atomicMin((int*)&mnb[row], __float_as_int(mm));  // values >= 0
  }
}

// ---- LDS-privatized accumulation; merge = plain store (partial) or atomic ----
template <int G, int S, bool ATOMIC>
__global__ __launch_bounds__(1024) void accum_kernel(
    const float* __restrict__ in, int N, float vox,
    const u32* __restrict__ mnb, u64* __restrict__ Ap, u64* __restrict__ Bp) {
  extern __shared__ u64 lds[];
  u64* lA = lds;      // [G]  A = (ysum<<32)|xsum   (Q20)
  u64* lB = lds + G;  // [G]  B = (cnt <<32)|zsum
  int tid = threadIdx.x, b = blockIdx.y;
  for (int i = tid; i < G; i += 1024) { lA[i] = 0ull; lB[i] = 0ull; }
  __syncthreads();

  float m0 = __uint_as_float(mnb[b * 3 + 0]);
  float m1 = __uint_as_float(mnb[b * 3 + 1]);
  float m2 = __uint_as_float(mnb[b * 3 + 2]);
  int ppb = N / gridDim.x;
  const float* base = in + (size_t)b * 3 * N;
  int start = blockIdx.x * ppb;
  const float4* r0 = (const float4*)(base + start);
  const float4* r1 = (const float4*)(base + N + start);
  const float4* r2 = (const float4*)(base + 2 * N + start);
  int q4 = ppb >> 2;
  for (int i = tid; i < q4; i += 1024) {
    float4 X = r0[i], Y = r1[i], Z = r2[i];
#define PT(px, py, pz) { \
    int v0 = (int)floorf(((px) - m0) / vox); \
    int v1 = (int)floorf(((py) - m1) / vox); \
    int v2 = (int)floorf(((pz) - m2) / vox); \
    int lin = (v0 * S + v1) * S + v2; \
    u32 qx = (u32)((px) * 1048576.0f); \
    u32 qy = (u32)((py) * 1048576.0f); \
    u32 qz = (u32)((pz) * 1048576.0f); \
    atomicAdd(&lA[lin], ((u64)qy << 32) | (u64)qx); \
    atomicAdd(&lB[lin], (1ull << 32) | (u64)qz); }
    PT(X.x, Y.x, Z.x) PT(X.y, Y.y, Z.y) PT(X.z, Y.z, Z.z) PT(X.w, Y.w, Z.w)
#undef PT
  }
  __syncthreads();

  int p = ATOMIC ? 0 : blockIdx.x;
  u64* gA = Ap + ((size_t)p * 16 + b) * G;
  u64* gB = Bp + ((size_t)p * 16 + b) * G;
  for (int c = tid; c < G; c += 1024) {
    if (ATOMIC) {
      u64 Bv = lB[c];
      if (Bv) { atomicAdd(&gA[c], lA[c]); atomicAdd(&gB[c], Bv); }
    } else {
      gA[c] = lA[c];
      gB[c] = lB[c];
    }
  }
}

// ---- sum P partial slices -> per-cell float4 {mx,my,mz,cnt} ----
__global__ void reduce_kernel(int G, int P, const u64* __restrict__ Ap,
                              const u64* __restrict__ Bp,
                              float4* __restrict__ vox4) {
  int cell = blockIdx.x * 256 + threadIdx.x;
  int b = blockIdx.y;
  if (cell >= G) return;
  u64 A = 0ull, Bv = 0ull;
  for (int p = 0; p < P; ++p) {
    size_t o = ((size_t)p * 16 + b) * G + cell;
    A += Ap[o];
    Bv += Bp[o];
  }
  u32 cnt = (u32)(Bv >> 32);
  float4 o4 = make_float4(0.f, 0.f, 0.f, 0.f);
  if (cnt) {
    double inv = 1.0 / (1048576.0 * (double)cnt);
    o4.x = (float)((double)(u32)A * inv);
    o4.y = (float)((double)(u32)(A >> 32) * inv);
    o4.z = (float)((double)(u32)Bv * inv);
    o4.w = (float)cnt;
  }
  vox4[(size_t)b * G + cell] = o4;
}

// ---- ballot-scan compaction (ascending cell = JAX segment order) ----
template <bool FROMVOX>
__global__ __launch_bounds__(1024) void compact_kernel(
    int G, const float4* __restrict__ vox4, const u64* __restrict__ Ac,
    const u64* __restrict__ Bc, float4* __restrict__ means4,
    u32* __restrict__ numvox) {
  int b = blockIdx.x, tid = threadIdx.x, wid = tid >> 6, lane = tid & 63;
  __shared__ u32 wtot[16], wbase[16];
  __shared__ u32 gbase;
  if (tid == 0) gbase = 0u;
  __syncthreads();
  for (int t0 = 0; t0 < G; t0 += 1024) {
    int cell = t0 + tid;
    float4 v = make_float4(0.f, 0.f, 0.f, 0.f);
    u32 cnt = 0u;
    if (cell < G) {
      if (FROMVOX) {
        v = vox4[(size_t)b * G + cell];
        cnt = (u32)v.w;
      } else {
        u64 A = Ac[(size_t)b * G + cell], Bv = Bc[(size_t)b * G + cell];
        cnt = (u32)(Bv >> 32);
        if (cnt) {
          double inv = 1.0 / (1048576.0 * (double)cnt);
          v.x = (float)((double)(u32)A * inv);
          v.y = (float)((double)(u32)(A >> 32) * inv);
          v.z = (float)((double)(u32)Bv * inv);
        }
      }
    }
    bool occ = cnt > 0u;
    u64 mask = __ballot(occ);
    u32 prefix = (u32)__popcll(mask & ((1ull << lane) - 1ull));
    if (lane == 0) wtot[wid] = (u32)__popcll(mask);
    __syncthreads();
    if (tid == 0) {
      u32 s = gbase;
      for (int w = 0; w < 16; ++w) { wbase[w] = s; s += wtot[w]; }
      gbase = s;
    }
    __syncthreads();
    if (occ) means4[(size_t)b * G + wbase[wid] + prefix] = v;
    __syncthreads();
  }
  if (tid == 0) numvox[b] = gbase;
}

// ---- threefry sample: 1 output/thread, float4 gather, no atomics ----
__global__ void sample_kernel(int L, int G, const float4* __restrict__ means4,
                              const u32* __restrict__ numvox, KeyArr keys,
                              float* __restrict__ out) {
  int l = blockIdx.x * 256 + threadIdx.x;
  int b = blockIdx.y;
  u32 nv = numvox[b];
  uint32_t w0, w1;
  tf2x32(keys.k0[b], keys.k1[b], 0u, (uint32_t)l, w0, w1);
  uint32_t bits = w0 ^ w1;  // partitionable fold
  float u = __uint_as_float((bits >> 9) | 0x3F800000u) - 1.0f;
  int idx = (int)(u * (float)nv);  // f32 RN mul, trunc
  int nvm1 = (int)nv - 1;
  if (idx > nvm1) idx = nvm1;
  float4 m = means4[(size_t)b * G + idx];
  out[((size_t)b * 3 + 0) * L + l] = m.x;
  out[((size_t)b * 3 + 1) * L + l] = m.y;
  out[((size_t)b * 3 + 2) * L + l] = m.z;
}

extern "C" void kernel_launch(void* const* d_in, const int* in_sizes, int n_in,
                              void* d_out, int out_size, void* d_ws,
                              size_t ws_size, hipStream_t stream) {
  const float* x = (const float*)d_in[0];
  float* out = (float*)d_out;

  // ---- JAX key derivation (threefry partitionable split) ----
  uint32_t k1a, k1b, k2a, k2b;
  tf2x32(0u, 42u, 0u, 0u, k1a, k1b);
  tf2x32(0u, 42u, 0u, 1u, k2a, k2b);
  KeyArr keys1, keys2;
  for (int b = 0; b < 16; ++b) {
    tf2x32(k1a, k1b, 0u, (uint32_t)b, keys1.k0[b], keys1.k1[b]);
    tf2x32(k2a, k2b, 0u, (uint32_t)b, keys2.k0[b], keys2.k1[b]);
  }

  const int N1 = 262144, L1 = 131072, L2 = 65536, G1 = 8000, G2 = 1000;
  const size_t slice1 = (size_t)16 * G1, slice2 = (size_t)16 * G2;

  // big path: 16 partial slices (no global atomics) + vox4 + means4
  const size_t bigNeed = 2ull * 16 * slice1 * 8 + 2ull * slice1 * 16 + 4096;
  bool big = ws_size >= bigNeed;

  uint8_t* w = (uint8_t*)d_ws;
  u64 *Ap, *Bp;
  float4 *vox4 = nullptr, *means4;
  u32 *mnbits, *numvox;
  if (big) {
    Ap = (u64*)w;
    Bp = Ap + 16 * slice1;
    vox4 = (float4*)(Bp + 16 * slice1);
    means4 = vox4 + slice1;
    mnbits = (u32*)(means4 + slice1);
  } else {
    Ap = (u64*)w;                    // [slice1 | slice2] atomic cells
    Bp = Ap + (slice1 + slice2);
    means4 = (float4*)(Bp + (slice1 + slice2));
    mnbits = (u32*)(means4 + slice1);
  }
  numvox = mnbits + 96;

  int ncellsz = big ? 0 : (int)(slice1 + slice2);
  init_kernel<<<dim3(96), dim3(256), 0, stream>>>(Ap, Bp, ncellsz, mnbits,
                                                  numvox);

  // ---- layer 1: vox=0.05, S=20 (v<=19 proven), G=8000 ----
  min_kernel<<<dim3(64, 48), dim3(256), 0, stream>>>(x, N1 / 4, mnbits);
  if (big) {
    accum_kernel<G1, 20, false>
        <<<dim3(16, 16), dim3(1024), 2 * G1 * 8, stream>>>(x, N1, 0.05f,
                                                           mnbits, Ap, Bp);
    reduce_kernel<<<dim3((G1 + 255) / 256, 16), dim3(256), 0, stream>>>(
        G1, 16, Ap, Bp, vox4);
    compact_kernel<true><<<dim3(16), dim3(1024), 0, stream>>>(
        G1, vox4, nullptr, nullptr, means4, numvox);
  } else {
    accum_kernel<G1, 20, true>
        <<<dim3(8, 16), dim3(1024), 2 * G1 * 8, stream>>>(x, N1, 0.05f,
                                                          mnbits, Ap, Bp);
    compact_kernel<false><<<dim3(16), dim3(1024), 0, stream>>>(
        G1, nullptr, Ap, Bp, means4, numvox);
  }
  sample_kernel<<<dim3(L1 / 256, 16), dim3(256), 0, stream>>>(
      L1, G1, means4, numvox, keys1, out);

  // ---- layer 2: input = out1, vox=0.1, S=10 (v<=9), G=1000 ----
  float* out2 = out + (size_t)48 * L1;
  min_kernel<<<dim3(32, 48), dim3(256), 0, stream>>>(out, L1 / 4, mnbits + 48);
  if (big) {
    accum_kernel<G2, 10, false>
        <<<dim3(16, 16), dim3(1024), 2 * G2 * 8, stream>>>(out, L1, 0.1f,
                                                           mnbits + 48, Ap, Bp);
    reduce_kernel<<<dim3((G2 + 255) / 256, 16), dim3(256), 0, stream>>>(
        G2, 16, Ap, Bp, vox4);
    compact_kernel<true><<<dim3(16), dim3(1024), 0, stream>>>(
        G2, vox4, nullptr, nullptr, means4, numvox + 16);
  } else {
    accum_kernel<G2, 10, true>
        <<<dim3(8, 16), dim3(1024), 2 * G2 * 8, stream>>>(
            out, L1, 0.1f, mnbits + 48, Ap + slice1, Bp + slice1);
    compact_kernel<false><<<dim3(16), dim3(1024), 0, stream>>>(
        G2, nullptr, Ap + slice1, Bp + slice1, means4, numvox + 16);
  }
  sample_kernel<<<dim3(L2 / 256, 16), dim3(256), 0, stream>>>(
      L2, G2, means4, numvox + 16, keys2, out2);
}

// Round 5
// 96.010 us; speedup vs baseline: 3.5443x; 1.1615x over previous
//
#include <hip/hip_runtime.h>
#include <stdint.h>

// VoxelLayer: JAX voxel-grid downsample ×2, bit-exact Threefry-2x32
// (partitionable) sampling. Round 5: 4-wide sample (no atomic tail),
// ILP-8 min, 1-block init on big path.

typedef unsigned int u32;
typedef unsigned long long u64;

struct KeyArr { uint32_t k0[16]; uint32_t k1[16]; };

__host__ __device__ inline void tf2x32(uint32_t k0, uint32_t k1,
                                       uint32_t c0, uint32_t c1,
                                       uint32_t& o0, uint32_t& o1) {
  const uint32_t ks0 = k0, ks1 = k1, ks2 = k0 ^ k1 ^ 0x1BD11BDAu;
  uint32_t x0 = c0 + ks0, x1 = c1 + ks1;
#define TF_R(r) { x0 += x1; x1 = (x1 << (r)) | (x1 >> (32 - (r))); x1 ^= x0; }
  TF_R(13) TF_R(15) TF_R(26) TF_R(6)
  x0 += ks1; x1 += ks2 + 1u;
  TF_R(17) TF_R(29) TF_R(16) TF_R(24)
  x0 += ks2; x1 += ks0 + 2u;
  TF_R(13) TF_R(15) TF_R(26) TF_R(6)
  x0 += ks0; x1 += ks1 + 3u;
  TF_R(17) TF_R(29) TF_R(16) TF_R(24)
  x0 += ks1; x1 += ks2 + 4u;
  TF_R(13) TF_R(15) TF_R(26) TF_R(6)
  x0 += ks2; x1 += ks0 + 5u;
#undef TF_R
  o0 = x0; o1 = x1;
}

// ---- init: zero cells (atomic path only), min=+inf, numvox=0 ----
__global__ void init_kernel(u64* cellsA, u64* cellsB, int ncells,
                            u32* mnbits, u32* numvox) {
  int i = blockIdx.x * blockDim.x + threadIdx.x;
  int stride = gridDim.x * blockDim.x;
  for (int j = i; j < ncells; j += stride) { cellsA[j] = 0ull; cellsB[j] = 0ull; }
  if (i < 96) mnbits[i] = 0x7F800000u;  // +inf
  if (i < 32) numvox[i] = 0u;
}

// ---- per-(batch,coord) min: ILP-8 float4 loads, block-reduce, 1 atomic ----
__global__ void min_kernel(const float* __restrict__ in, int n4,
                           u32* __restrict__ mnb) {
  int row = blockIdx.y;  // b*3+c in [0,48)
  const float4* p = (const float4*)in + (size_t)row * n4;
  int base = blockIdx.x * 2048 + threadIdx.x;
  float4 v0 = p[base];
  float4 v1 = p[base + 256];
  float4 v2 = p[base + 512];
  float4 v3 = p[base + 768];
  float4 v4 = p[base + 1024];
  float4 v5 = p[base + 1280];
  float4 v6 = p[base + 1536];
  float4 v7 = p[base + 1792];
  float m0 = fminf(fminf(v0.x, v0.y), fminf(v0.z, v0.w));
  float m1 = fminf(fminf(v1.x, v1.y), fminf(v1.z, v1.w));
  float m2 = fminf(fminf(v2.x, v2.y), fminf(v2.z, v2.w));
  float m3 = fminf(fminf(v3.x, v3.y), fminf(v3.z, v3.w));
  float m4 = fminf(fminf(v4.x, v4.y), fminf(v4.z, v4.w));
  float m5 = fminf(fminf(v5.x, v5.y), fminf(v5.z, v5.w));
  float m6 = fminf(fminf(v6.x, v6.y), fminf(v6.z, v6.w));
  float m7 = fminf(fminf(v7.x, v7.y), fminf(v7.z, v7.w));
  float m = fminf(fminf(fminf(m0, m1), fminf(m2, m3)),
                  fminf(fminf(m4, m5), fminf(m6, m7)));
  for (int off = 32; off > 0; off >>= 1)
    m = fminf(m, __shfl_down(m, off, 64));
  __shared__ float wmin[4];
  int wid = threadIdx.x >> 6;
  if ((threadIdx.x & 63) == 0) wmin[wid] = m;
  __syncthreads();
  if (threadIdx.x == 0) {
    float mm = fminf(fminf(wmin[0], wmin[1]), fminf(wmin[2], wmin[3]));
    atomicMin((int*)&mnb[row], __float_as_int(mm));  // values >= 0
  }
}

// ---- LDS-privatized accumulation; merge = plain store (partial) or atomic ----
template <int G, int S, bool ATOMIC>
__global__ __launch_bounds__(1024) void accum_kernel(
    const float* __restrict__ in, int N, float vox,
    const u32* __restrict__ mnb, u64* __restrict__ Ap, u64* __restrict__ Bp) {
  extern __shared__ u64 lds[];
  u64* lA = lds;      // [G]  A = (ysum<<32)|xsum   (Q20)
  u64* lB = lds + G;  // [G]  B = (cnt <<32)|zsum
  int tid = threadIdx.x, b = blockIdx.y;
  for (int i = tid; i < G; i += 1024) { lA[i] = 0ull; lB[i] = 0ull; }
  __syncthreads();

  float m0 = __uint_as_float(mnb[b * 3 + 0]);
  float m1 = __uint_as_float(mnb[b * 3 + 1]);
  float m2 = __uint_as_float(mnb[b * 3 + 2]);
  int ppb = N / gridDim.x;
  const float* base = in + (size_t)b * 3 * N;
  int start = blockIdx.x * ppb;
  const float4* r0 = (const float4*)(base + start);
  const float4* r1 = (const float4*)(base + N + start);
  const float4* r2 = (const float4*)(base + 2 * N + start);
  int q4 = ppb >> 2;
  for (int i = tid; i < q4; i += 1024) {
    float4 X = r0[i], Y = r1[i], Z = r2[i];
#define PT(px, py, pz) { \
    int v0 = (int)floorf(((px) - m0) / vox); \
    int v1 = (int)floorf(((py) - m1) / vox); \
    int v2 = (int)floorf(((pz) - m2) / vox); \
    int lin = (v0 * S + v1) * S + v2; \
    u32 qx = (u32)((px) * 1048576.0f); \
    u32 qy = (u32)((py) * 1048576.0f); \
    u32 qz = (u32)((pz) * 1048576.0f); \
    atomicAdd(&lA[lin], ((u64)qy << 32) | (u64)qx); \
    atomicAdd(&lB[lin], (1ull << 32) | (u64)qz); }
    PT(X.x, Y.x, Z.x) PT(X.y, Y.y, Z.y) PT(X.z, Y.z, Z.z) PT(X.w, Y.w, Z.w)
#undef PT
  }
  __syncthreads();

  int p = ATOMIC ? 0 : blockIdx.x;
  u64* gA = Ap + ((size_t)p * 16 + b) * G;
  u64* gB = Bp + ((size_t)p * 16 + b) * G;
  for (int c = tid; c < G; c += 1024) {
    if (ATOMIC) {
      u64 Bv = lB[c];
      if (Bv) { atomicAdd(&gA[c], lA[c]); atomicAdd(&gB[c], Bv); }
    } else {
      gA[c] = lA[c];
      gB[c] = lB[c];
    }
  }
}

// ---- sum P partial slices -> per-cell float4 {mx,my,mz,cnt} ----
__global__ void reduce_kernel(int G, int P, const u64* __restrict__ Ap,
                              const u64* __restrict__ Bp,
                              float4* __restrict__ vox4) {
  int cell = blockIdx.x * 256 + threadIdx.x;
  int b = blockIdx.y;
  if (cell >= G) return;
  u64 A = 0ull, Bv = 0ull;
  for (int p = 0; p < P; ++p) {
    size_t o = ((size_t)p * 16 + b) * G + cell;
    A += Ap[o];
    Bv += Bp[o];
  }
  u32 cnt = (u32)(Bv >> 32);
  float4 o4 = make_float4(0.f, 0.f, 0.f, 0.f);
  if (cnt) {
    double inv = 1.0 / (1048576.0 * (double)cnt);
    o4.x = (float)((double)(u32)A * inv);
    o4.y = (float)((double)(u32)(A >> 32) * inv);
    o4.z = (float)((double)(u32)Bv * inv);
    o4.w = (float)cnt;
  }
  vox4[(size_t)b * G + cell] = o4;
}

// ---- ballot-scan compaction (ascending cell = JAX segment order) ----
template <bool FROMVOX>
__global__ __launch_bounds__(1024) void compact_kernel(
    int G, const float4* __restrict__ vox4, const u64* __restrict__ Ac,
    const u64* __restrict__ Bc, float4* __restrict__ means4,
    u32* __restrict__ numvox) {
  int b = blockIdx.x, tid = threadIdx.x, wid = tid >> 6, lane = tid & 63;
  __shared__ u32 wtot[16], wbase[16];
  __shared__ u32 gbase;
  if (tid == 0) gbase = 0u;
  __syncthreads();
  for (int t0 = 0; t0 < G; t0 += 1024) {
    int cell = t0 + tid;
    float4 v = make_float4(0.f, 0.f, 0.f, 0.f);
    u32 cnt = 0u;
    if (cell < G) {
      if (FROMVOX) {
        v = vox4[(size_t)b * G + cell];
        cnt = (u32)v.w;
      } else {
        u64 A = Ac[(size_t)b * G + cell], Bv = Bc[(size_t)b * G + cell];
        cnt = (u32)(Bv >> 32);
        if (cnt) {
          double inv = 1.0 / (1048576.0 * (double)cnt);
          v.x = (float)((double)(u32)A * inv);
          v.y = (float)((double)(u32)(A >> 32) * inv);
          v.z = (float)((double)(u32)Bv * inv);
        }
      }
    }
    bool occ = cnt > 0u;
    u64 mask = __ballot(occ);
    u32 prefix = (u32)__popcll(mask & ((1ull << lane) - 1ull));
    if (lane == 0) wtot[wid] = (u32)__popcll(mask);
    __syncthreads();
    if (tid == 0) {
      u32 s = gbase;
      for (int w = 0; w < 16; ++w) { wbase[w] = s; s += wtot[w]; }
      gbase = s;
    }
    __syncthreads();
    if (occ) means4[(size_t)b * G + wbase[wid] + prefix] = v;
    __syncthreads();
  }
  if (tid == 0) numvox[b] = gbase;
}

// ---- threefry sample: 4 outputs/thread, float4 gathers + float4 stores ----
__global__ void sample_kernel(int L, int G, const float4* __restrict__ means4,
                              const u32* __restrict__ numvox, KeyArr keys,
                              float* __restrict__ out) {
  int t = blockIdx.x * 256 + threadIdx.x;
  int b = blockIdx.y;
  int l0 = t * 4;  // L multiple of 1024 -> no tail guard
  u32 nv = numvox[b];
  float fnv = (float)nv;
  int nvm1 = (int)nv - 1;
  uint32_t K0 = keys.k0[b], K1 = keys.k1[b];
  float4 m[4];
#pragma unroll
  for (int j = 0; j < 4; ++j) {
    uint32_t w0, w1;
    tf2x32(K0, K1, 0u, (uint32_t)(l0 + j), w0, w1);
    uint32_t bits = w0 ^ w1;  // partitionable fold
    float u = __uint_as_float((bits >> 9) | 0x3F800000u) - 1.0f;
    int idx = (int)(u * fnv);  // f32 RN mul, trunc
    if (idx > nvm1) idx = nvm1;
    m[j] = means4[(size_t)b * G + idx];
  }
  *(float4*)(out + ((size_t)b * 3 + 0) * L + l0) =
      make_float4(m[0].x, m[1].x, m[2].x, m[3].x);
  *(float4*)(out + ((size_t)b * 3 + 1) * L + l0) =
      make_float4(m[0].y, m[1].y, m[2].y, m[3].y);
  *(float4*)(out + ((size_t)b * 3 + 2) * L + l0) =
      make_float4(m[0].z, m[1].z, m[2].z, m[3].z);
}

extern "C" void kernel_launch(void* const* d_in, const int* in_sizes, int n_in,
                              void* d_out, int out_size, void* d_ws,
                              size_t ws_size, hipStream_t stream) {
  const float* x = (const float*)d_in[0];
  float* out = (float*)d_out;

  // ---- JAX key derivation (threefry partitionable split) ----
  uint32_t k1a, k1b, k2a, k2b;
  tf2x32(0u, 42u, 0u, 0u, k1a, k1b);
  tf2x32(0u, 42u, 0u, 1u, k2a, k2b);
  KeyArr keys1, keys2;
  for (int b = 0; b < 16; ++b) {
    tf2x32(k1a, k1b, 0u, (uint32_t)b, keys1.k0[b], keys1.k1[b]);
    tf2x32(k2a, k2b, 0u, (uint32_t)b, keys2.k0[b], keys2.k1[b]);
  }

  const int N1 = 262144, L1 = 131072, L2 = 65536, G1 = 8000, G2 = 1000;
  const size_t slice1 = (size_t)16 * G1, slice2 = (size_t)16 * G2;

  // big path: 16 partial slices (no global atomics) + vox4 + means4
  const size_t bigNeed = 2ull * 16 * slice1 * 8 + 2ull * slice1 * 16 + 4096;
  bool big = ws_size >= bigNeed;

  uint8_t* w = (uint8_t*)d_ws;
  u64 *Ap, *Bp;
  float4 *vox4 = nullptr, *means4;
  u32 *mnbits, *numvox;
  if (big) {
    Ap = (u64*)w;
    Bp = Ap + 16 * slice1;
    vox4 = (float4*)(Bp + 16 * slice1);
    means4 = vox4 + slice1;
    mnbits = (u32*)(means4 + slice1);
  } else {
    Ap = (u64*)w;                    // [slice1 | slice2] atomic cells
    Bp = Ap + (slice1 + slice2);
    means4 = (float4*)(Bp + (slice1 + slice2));
    mnbits = (u32*)(means4 + slice1);
  }
  numvox = mnbits + 96;

  if (big) {
    init_kernel<<<dim3(1), dim3(128), 0, stream>>>(Ap, Bp, 0, mnbits, numvox);
  } else {
    init_kernel<<<dim3(64), dim3(256), 0, stream>>>(
        Ap, Bp, (int)(slice1 + slice2), mnbits, numvox);
  }

  // ---- layer 1: vox=0.05, S=20 (v<=19 proven), G=8000 ----
  min_kernel<<<dim3(32, 48), dim3(256), 0, stream>>>(x, N1 / 4, mnbits);
  if (big) {
    accum_kernel<G1, 20, false>
        <<<dim3(16, 16), dim3(1024), 2 * G1 * 8, stream>>>(x, N1, 0.05f,
                                                           mnbits, Ap, Bp);
    reduce_kernel<<<dim3((G1 + 255) / 256, 16), dim3(256), 0, stream>>>(
        G1, 16, Ap, Bp, vox4);
    compact_kernel<true><<<dim3(16), dim3(1024), 0, stream>>>(
        G1, vox4, nullptr, nullptr, means4, numvox);
  } else {
    accum_kernel<G1, 20, true>
        <<<dim3(8, 16), dim3(1024), 2 * G1 * 8, stream>>>(x, N1, 0.05f,
                                                          mnbits, Ap, Bp);
    compact_kernel<false><<<dim3(16), dim3(1024), 0, stream>>>(
        G1, nullptr, Ap, Bp, means4, numvox);
  }
  sample_kernel<<<dim3(L1 / 1024, 16), dim3(256), 0, stream>>>(
      L1, G1, means4, numvox, keys1, out);

  // ---- layer 2: input = out1, vox=0.1, S=10 (v<=9), G=1000 ----
  float* out2 = out + (size_t)48 * L1;
  min_kernel<<<dim3(16, 48), dim3(256), 0, stream>>>(out, L1 / 4, mnbits + 48);
  if (big) {
    accum_kernel<G2, 10, false>
        <<<dim3(16, 16), dim3(1024), 2 * G2 * 8, stream>>>(out, L1, 0.1f,
                                                           mnbits + 48, Ap, Bp);
    reduce_kernel<<<dim3((G2 + 255) / 256, 16), dim3(256), 0, stream>>>(
        G2, 16, Ap, Bp, vox4);
    compact_kernel<true><<<dim3(16), dim3(1024), 0, stream>>>(
        G2, vox4, nullptr, nullptr, means4, numvox + 16);
  } else {
    accum_kernel<G2, 10, true>
        <<<dim3(8, 16), dim3(1024), 2 * G2 * 8, stream>>>(
            out, L1, 0.1f, mnbits + 48, Ap + slice1, Bp + slice1);
    compact_kernel<false><<<dim3(16), dim3(1024), 0, stream>>>(
        G2, nullptr, Ap + slice1, Bp + slice1, means4, numvox + 16);
  }
  sample_kernel<<<dim3(L2 / 1024, 16), dim3(256), 0, stream>>>(
      L2, G2, means4, numvox + 16, keys2, out2);
}

// Round 6
// 84.286 us; speedup vs baseline: 4.0373x; 1.1391x over previous
//
#include <hip/hip_runtime.h>
#include <stdint.h>

// VoxelLayer: JAX voxel-grid downsample ×2, bit-exact Threefry-2x32
// (partitionable) sampling. Round 6: two-phase parallel compaction (count
// fused into reduce), atomic-free partial-min (init dispatch removed on
// big path).

typedef unsigned int u32;
typedef unsigned long long u64;

struct KeyArr { uint32_t k0[16]; uint32_t k1[16]; };

__host__ __device__ inline void tf2x32(uint32_t k0, uint32_t k1,
                                       uint32_t c0, uint32_t c1,
                                       uint32_t& o0, uint32_t& o1) {
  const uint32_t ks0 = k0, ks1 = k1, ks2 = k0 ^ k1 ^ 0x1BD11BDAu;
  uint32_t x0 = c0 + ks0, x1 = c1 + ks1;
#define TF_R(r) { x0 += x1; x1 = (x1 << (r)) | (x1 >> (32 - (r))); x1 ^= x0; }
  TF_R(13) TF_R(15) TF_R(26) TF_R(6)
  x0 += ks1; x1 += ks2 + 1u;
  TF_R(17) TF_R(29) TF_R(16) TF_R(24)
  x0 += ks2; x1 += ks0 + 2u;
  TF_R(13) TF_R(15) TF_R(26) TF_R(6)
  x0 += ks0; x1 += ks1 + 3u;
  TF_R(17) TF_R(29) TF_R(16) TF_R(24)
  x0 += ks1; x1 += ks2 + 4u;
  TF_R(13) TF_R(15) TF_R(26) TF_R(6)
  x0 += ks2; x1 += ks0 + 5u;
#undef TF_R
  o0 = x0; o1 = x1;
}

// ---- init (small path only): zero atomic cells ----
__global__ void init_kernel(u64* cellsA, u64* cellsB, int ncells) {
  int i = blockIdx.x * blockDim.x + threadIdx.x;
  int stride = gridDim.x * blockDim.x;
  for (int j = i; j < ncells; j += stride) { cellsA[j] = 0ull; cellsB[j] = 0ull; }
}

// ---- per-(batch,coord) min: ILP-8, per-block partial store (no atomics) ----
__global__ void min_kernel(const float* __restrict__ in, int n4,
                           float* __restrict__ pmin) {
  int row = blockIdx.y;  // b*3+c in [0,48)
  int PB = gridDim.x;
  const float4* p = (const float4*)in + (size_t)row * n4;
  int base = blockIdx.x * 2048 + threadIdx.x;
  float4 v0 = p[base];
  float4 v1 = p[base + 256];
  float4 v2 = p[base + 512];
  float4 v3 = p[base + 768];
  float4 v4 = p[base + 1024];
  float4 v5 = p[base + 1280];
  float4 v6 = p[base + 1536];
  float4 v7 = p[base + 1792];
  float m0 = fminf(fminf(v0.x, v0.y), fminf(v0.z, v0.w));
  float m1 = fminf(fminf(v1.x, v1.y), fminf(v1.z, v1.w));
  float m2 = fminf(fminf(v2.x, v2.y), fminf(v2.z, v2.w));
  float m3 = fminf(fminf(v3.x, v3.y), fminf(v3.z, v3.w));
  float m4 = fminf(fminf(v4.x, v4.y), fminf(v4.z, v4.w));
  float m5 = fminf(fminf(v5.x, v5.y), fminf(v5.z, v5.w));
  float m6 = fminf(fminf(v6.x, v6.y), fminf(v6.z, v6.w));
  float m7 = fminf(fminf(v7.x, v7.y), fminf(v7.z, v7.w));
  float m = fminf(fminf(fminf(m0, m1), fminf(m2, m3)),
                  fminf(fminf(m4, m5), fminf(m6, m7)));
  for (int off = 32; off > 0; off >>= 1)
    m = fminf(m, __shfl_down(m, off, 64));
  __shared__ float wmin[4];
  int wid = threadIdx.x >> 6;
  if ((threadIdx.x & 63) == 0) wmin[wid] = m;
  __syncthreads();
  if (threadIdx.x == 0)
    pmin[row * PB + blockIdx.x] =
        fminf(fminf(wmin[0], wmin[1]), fminf(wmin[2], wmin[3]));
}

// ---- LDS-privatized accumulation; merge = plain store (partial) or atomic ----
template <int G, int S, bool ATOMIC>
__global__ __launch_bounds__(1024) void accum_kernel(
    const float* __restrict__ in, int N, float vox,
    const float* __restrict__ pmin, int PB, u64* __restrict__ Ap,
    u64* __restrict__ Bp) {
  extern __shared__ u64 lds[];
  u64* lA = lds;      // [G]  A = (ysum<<32)|xsum   (Q20)
  u64* lB = lds + G;  // [G]  B = (cnt <<32)|zsum
  int tid = threadIdx.x, b = blockIdx.y;
  for (int i = tid; i < G; i += 1024) { lA[i] = 0ull; lB[i] = 0ull; }

  // reduce per-block partial mins (uniform; L1/L2 broadcast)
  float m0 = __int_as_float(0x7F800000), m1 = m0, m2 = m0;
  for (int j = 0; j < PB; ++j) {
    m0 = fminf(m0, pmin[(b * 3 + 0) * PB + j]);
    m1 = fminf(m1, pmin[(b * 3 + 1) * PB + j]);
    m2 = fminf(m2, pmin[(b * 3 + 2) * PB + j]);
  }
  __syncthreads();

  int ppb = N / gridDim.x;
  const float* base = in + (size_t)b * 3 * N;
  int start = blockIdx.x * ppb;
  const float4* r0 = (const float4*)(base + start);
  const float4* r1 = (const float4*)(base + N + start);
  const float4* r2 = (const float4*)(base + 2 * N + start);
  int q4 = ppb >> 2;
  for (int i = tid; i < q4; i += 1024) {
    float4 X = r0[i], Y = r1[i], Z = r2[i];
#define PT(px, py, pz) { \
    int v0 = (int)floorf(((px) - m0) / vox); \
    int v1 = (int)floorf(((py) - m1) / vox); \
    int v2 = (int)floorf(((pz) - m2) / vox); \
    int lin = (v0 * S + v1) * S + v2; \
    u32 qx = (u32)((px) * 1048576.0f); \
    u32 qy = (u32)((py) * 1048576.0f); \
    u32 qz = (u32)((pz) * 1048576.0f); \
    atomicAdd(&lA[lin], ((u64)qy << 32) | (u64)qx); \
    atomicAdd(&lB[lin], (1ull << 32) | (u64)qz); }
    PT(X.x, Y.x, Z.x) PT(X.y, Y.y, Z.y) PT(X.z, Y.z, Z.z) PT(X.w, Y.w, Z.w)
#undef PT
  }
  __syncthreads();

  int p = ATOMIC ? 0 : blockIdx.x;
  u64* gA = Ap + ((size_t)p * 16 + b) * G;
  u64* gB = Bp + ((size_t)p * 16 + b) * G;
  for (int c = tid; c < G; c += 1024) {
    if (ATOMIC) {
      u64 Bv = lB[c];
      if (Bv) { atomicAdd(&gA[c], lA[c]); atomicAdd(&gB[c], Bv); }
    } else {
      gA[c] = lA[c];
      gB[c] = lB[c];
    }
  }
}

// ---- sum P partials -> per-cell float4 {mx,my,mz,cnt} + per-block occ count ----
__global__ void reduce_kernel(int G, int P, const u64* __restrict__ Ap,
                              const u64* __restrict__ Bp,
                              float4* __restrict__ vox4,
                              u32* __restrict__ bcnt) {
  int blk = blockIdx.x, b = blockIdx.y, tid = threadIdx.x;
  int cell = blk * 256 + tid;
  u64 A = 0ull, Bv = 0ull;
  if (cell < G) {
    for (int p = 0; p < P; ++p) {
      size_t o = ((size_t)p * 16 + b) * G + cell;
      A += Ap[o];
      Bv += Bp[o];
    }
  }
  u32 cnt = (u32)(Bv >> 32);
  if (cell < G) {
    float4 o4 = make_float4(0.f, 0.f, 0.f, 0.f);
    if (cnt) {
      double inv = 1.0 / (1048576.0 * (double)cnt);
      o4.x = (float)((double)(u32)A * inv);
      o4.y = (float)((double)(u32)(A >> 32) * inv);
      o4.z = (float)((double)(u32)Bv * inv);
      o4.w = (float)cnt;
    }
    vox4[(size_t)b * G + cell] = o4;
  }
  // per-block occupancy count (all threads participate)
  u64 mask = __ballot(cnt > 0u);
  __shared__ u32 wtot[4];
  if ((tid & 63) == 0) wtot[tid >> 6] = (u32)__popcll(mask);
  __syncthreads();
  if (tid == 0)
    bcnt[b * gridDim.x + blk] = wtot[0] + wtot[1] + wtot[2] + wtot[3];
}

// ---- parallel compaction: per-block base from bcnt, ballot-compact ----
__global__ void compact_b_kernel(int G, const float4* __restrict__ vox4,
                                 const u32* __restrict__ bcnt,
                                 float4* __restrict__ means4,
                                 u32* __restrict__ numvox) {
  int blk = blockIdx.x, nb = gridDim.x, b = blockIdx.y, tid = threadIdx.x;
  int lane = tid & 63, wid = tid >> 6;
  int cell = blk * 256 + tid;
  float4 v = make_float4(0.f, 0.f, 0.f, 0.f);
  bool occ = false;
  if (cell < G) {
    v = vox4[(size_t)b * G + cell];
    occ = v.w > 0.f;
  }
  u64 mask = __ballot(occ);
  u32 prefix = (u32)__popcll(mask & ((1ull << lane) - 1ull));
  __shared__ u32 wb[4];
  if (lane == 0) wb[wid] = (u32)__popcll(mask);
  __syncthreads();
  if (tid == 0) {
    u32 base = 0;
    for (int j = 0; j < blk; ++j) base += bcnt[b * nb + j];
    u32 s = base;
    for (int w = 0; w < 4; ++w) { u32 t = wb[w]; wb[w] = s; s += t; }
    if (blk == nb - 1) numvox[b] = s;
  }
  __syncthreads();
  if (occ) means4[(size_t)b * G + wb[wid] + prefix] = v;
}

// ---- serial-scan compaction (small/atomic path only) ----
__global__ __launch_bounds__(1024) void compact_kernel(
    int G, const u64* __restrict__ Ac, const u64* __restrict__ Bc,
    float4* __restrict__ means4, u32* __restrict__ numvox) {
  int b = blockIdx.x, tid = threadIdx.x, wid = tid >> 6, lane = tid & 63;
  __shared__ u32 wtot[16], wbase[16];
  __shared__ u32 gbase;
  if (tid == 0) gbase = 0u;
  __syncthreads();
  for (int t0 = 0; t0 < G; t0 += 1024) {
    int cell = t0 + tid;
    float4 v = make_float4(0.f, 0.f, 0.f, 0.f);
    u32 cnt = 0u;
    if (cell < G) {
      u64 A = Ac[(size_t)b * G + cell], Bv = Bc[(size_t)b * G + cell];
      cnt = (u32)(Bv >> 32);
      if (cnt) {
        double inv = 1.0 / (1048576.0 * (double)cnt);
        v.x = (float)((double)(u32)A * inv);
        v.y = (float)((double)(u32)(A >> 32) * inv);
        v.z = (float)((double)(u32)Bv * inv);
      }
    }
    bool occ = cnt > 0u;
    u64 mask = __ballot(occ);
    u32 prefix = (u32)__popcll(mask & ((1ull << lane) - 1ull));
    if (lane == 0) wtot[wid] = (u32)__popcll(mask);
    __syncthreads();
    if (tid == 0) {
      u32 s = gbase;
      for (int w = 0; w < 16; ++w) { wbase[w] = s; s += wtot[w]; }
      gbase = s;
    }
    __syncthreads();
    if (occ) means4[(size_t)b * G + wbase[wid] + prefix] = v;
    __syncthreads();
  }
  if (tid == 0) numvox[b] = gbase;
}

// ---- threefry sample: 4 outputs/thread, float4 gathers + float4 stores ----
__global__ void sample_kernel(int L, int G, const float4* __restrict__ means4,
                              const u32* __restrict__ numvox, KeyArr keys,
                              float* __restrict__ out) {
  int t = blockIdx.x * 256 + threadIdx.x;
  int b = blockIdx.y;
  int l0 = t * 4;  // L multiple of 1024 -> no tail guard
  u32 nv = numvox[b];
  float fnv = (float)nv;
  int nvm1 = (int)nv - 1;
  uint32_t K0 = keys.k0[b], K1 = keys.k1[b];
  float4 m[4];
#pragma unroll
  for (int j = 0; j < 4; ++j) {
    uint32_t w0, w1;
    tf2x32(K0, K1, 0u, (uint32_t)(l0 + j), w0, w1);
    uint32_t bits = w0 ^ w1;  // partitionable fold
    float u = __uint_as_float((bits >> 9) | 0x3F800000u) - 1.0f;
    int idx = (int)(u * fnv);  // f32 RN mul, trunc
    if (idx > nvm1) idx = nvm1;
    m[j] = means4[(size_t)b * G + idx];
  }
  *(float4*)(out + ((size_t)b * 3 + 0) * L + l0) =
      make_float4(m[0].x, m[1].x, m[2].x, m[3].x);
  *(float4*)(out + ((size_t)b * 3 + 1) * L + l0) =
      make_float4(m[0].y, m[1].y, m[2].y, m[3].y);
  *(float4*)(out + ((size_t)b * 3 + 2) * L + l0) =
      make_float4(m[0].z, m[1].z, m[2].z, m[3].z);
}

extern "C" void kernel_launch(void* const* d_in, const int* in_sizes, int n_in,
                              void* d_out, int out_size, void* d_ws,
                              size_t ws_size, hipStream_t stream) {
  const float* x = (const float*)d_in[0];
  float* out = (float*)d_out;

  // ---- JAX key derivation (threefry partitionable split) ----
  uint32_t k1a, k1b, k2a, k2b;
  tf2x32(0u, 42u, 0u, 0u, k1a, k1b);
  tf2x32(0u, 42u, 0u, 1u, k2a, k2b);
  KeyArr keys1, keys2;
  for (int b = 0; b < 16; ++b) {
    tf2x32(k1a, k1b, 0u, (uint32_t)b, keys1.k0[b], keys1.k1[b]);
    tf2x32(k2a, k2b, 0u, (uint32_t)b, keys2.k0[b], keys2.k1[b]);
  }

  const int N1 = 262144, L1 = 131072, L2 = 65536, G1 = 8000, G2 = 1000;
  const int PB1 = 32, PB2 = 16, NB1 = 32, NB2 = 4;
  const size_t slice1 = (size_t)16 * G1, slice2 = (size_t)16 * G2;

  // big path: 16 partial slices (no global atomics) + vox4 + means4
  const size_t tailBytes = (48 * PB1 + 48 * PB2 + 16 * NB1 + 32) * 4 + 256;
  const size_t bigNeed =
      2ull * 16 * slice1 * 8 + 2ull * slice1 * 16 + tailBytes;
  bool big = ws_size >= bigNeed;

  uint8_t* w = (uint8_t*)d_ws;
  u64 *Ap, *Bp;
  float4 *vox4 = nullptr, *means4;
  uint8_t* tail;
  if (big) {
    Ap = (u64*)w;
    Bp = Ap + 16 * slice1;
    vox4 = (float4*)(Bp + 16 * slice1);
    means4 = vox4 + slice1;
    tail = (uint8_t*)(means4 + slice1);
  } else {
    Ap = (u64*)w;                    // [slice1 | slice2] atomic cells
    Bp = Ap + (slice1 + slice2);
    means4 = (float4*)(Bp + (slice1 + slice2));
    tail = (uint8_t*)(means4 + slice1);
  }
  float* pmin1 = (float*)tail;                 // 48*PB1
  float* pmin2 = pmin1 + 48 * PB1;             // 48*PB2
  u32* bcnt = (u32*)(pmin2 + 48 * PB2);        // 16*NB1
  u32* numvox = bcnt + 16 * NB1;               // 32

  if (!big) {
    init_kernel<<<dim3(64), dim3(256), 0, stream>>>(
        Ap, Bp, (int)(slice1 + slice2));
  }

  // ---- layer 1: vox=0.05, S=20 (v<=19 proven), G=8000 ----
  min_kernel<<<dim3(PB1, 48), dim3(256), 0, stream>>>(x, N1 / 4, pmin1);
  if (big) {
    accum_kernel<G1, 20, false>
        <<<dim3(16, 16), dim3(1024), 2 * G1 * 8, stream>>>(x, N1, 0.05f,
                                                           pmin1, PB1, Ap, Bp);
    reduce_kernel<<<dim3(NB1, 16), dim3(256), 0, stream>>>(G1, 16, Ap, Bp,
                                                           vox4, bcnt);
    compact_b_kernel<<<dim3(NB1, 16), dim3(256), 0, stream>>>(
        G1, vox4, bcnt, means4, numvox);
  } else {
    accum_kernel<G1, 20, true>
        <<<dim3(8, 16), dim3(1024), 2 * G1 * 8, stream>>>(x, N1, 0.05f, pmin1,
                                                          PB1, Ap, Bp);
    compact_kernel<<<dim3(16), dim3(1024), 0, stream>>>(G1, Ap, Bp, means4,
                                                        numvox);
  }
  sample_kernel<<<dim3(L1 / 1024, 16), dim3(256), 0, stream>>>(
      L1, G1, means4, numvox, keys1, out);

  // ---- layer 2: input = out1, vox=0.1, S=10 (v<=9), G=1000 ----
  float* out2 = out + (size_t)48 * L1;
  min_kernel<<<dim3(PB2, 48), dim3(256), 0, stream>>>(out, L1 / 4, pmin2);
  if (big) {
    accum_kernel<G2, 10, false>
        <<<dim3(16, 16), dim3(1024), 2 * G2 * 8, stream>>>(
            out, L1, 0.1f, pmin2, PB2, Ap, Bp);
    reduce_kernel<<<dim3(NB2, 16), dim3(256), 0, stream>>>(G2, 16, Ap, Bp,
                                                           vox4, bcnt);
    compact_b_kernel<<<dim3(NB2, 16), dim3(256), 0, stream>>>(
        G2, vox4, bcnt, means4, numvox + 16);
  } else {
    accum_kernel<G2, 10, true>
        <<<dim3(8, 16), dim3(1024), 2 * G2 * 8, stream>>>(
            out, L1, 0.1f, pmin2, PB2, Ap + slice1, Bp + slice1);
    compact_kernel<<<dim3(16), dim3(1024), 0, stream>>>(
        G2, Ap + slice1, Bp + slice1, means4, numvox + 16);
  }
  sample_kernel<<<dim3(L2 / 1024, 16), dim3(256), 0, stream>>>(
      L2, G2, means4, numvox + 16, keys2, out2);
}

// Round 7
// 71.922 us; speedup vs baseline: 4.7313x; 1.1719x over previous
//
#include <hip/hip_runtime.h>
#include <stdint.h>

// VoxelLayer: JAX voxel-grid downsample ×2, bit-exact Threefry-2x32
// (partitionable) sampling. Round 7: min2 fused into sample1 (plain
// partial stores, NOT round-3's contended atomicMin), parallel pmin
// reduce in accum, fused reduce+compact for layer 2. 8 dispatches.

typedef unsigned int u32;
typedef unsigned long long u64;

struct KeyArr { uint32_t k0[16]; uint32_t k1[16]; };

__host__ __device__ inline void tf2x32(uint32_t k0, uint32_t k1,
                                       uint32_t c0, uint32_t c1,
                                       uint32_t& o0, uint32_t& o1) {
  const uint32_t ks0 = k0, ks1 = k1, ks2 = k0 ^ k1 ^ 0x1BD11BDAu;
  uint32_t x0 = c0 + ks0, x1 = c1 + ks1;
#define TF_R(r) { x0 += x1; x1 = (x1 << (r)) | (x1 >> (32 - (r))); x1 ^= x0; }
  TF_R(13) TF_R(15) TF_R(26) TF_R(6)
  x0 += ks1; x1 += ks2 + 1u;
  TF_R(17) TF_R(29) TF_R(16) TF_R(24)
  x0 += ks2; x1 += ks0 + 2u;
  TF_R(13) TF_R(15) TF_R(26) TF_R(6)
  x0 += ks0; x1 += ks1 + 3u;
  TF_R(17) TF_R(29) TF_R(16) TF_R(24)
  x0 += ks1; x1 += ks2 + 4u;
  TF_R(13) TF_R(15) TF_R(26) TF_R(6)
  x0 += ks2; x1 += ks0 + 5u;
#undef TF_R
  o0 = x0; o1 = x1;
}

// ---- init (small path only): zero atomic cells ----
__global__ void init_kernel(u64* cellsA, u64* cellsB, int ncells) {
  int i = blockIdx.x * blockDim.x + threadIdx.x;
  int stride = gridDim.x * blockDim.x;
  for (int j = i; j < ncells; j += stride) { cellsA[j] = 0ull; cellsB[j] = 0ull; }
}

// ---- per-(batch,coord) min: ILP-8, per-block partial store (no atomics) ----
__global__ void min_kernel(const float* __restrict__ in, int n4,
                           float* __restrict__ pmin) {
  int row = blockIdx.y;  // b*3+c in [0,48)
  int PB = gridDim.x;
  const float4* p = (const float4*)in + (size_t)row * n4;
  int base = blockIdx.x * 2048 + threadIdx.x;
  float4 v0 = p[base];
  float4 v1 = p[base + 256];
  float4 v2 = p[base + 512];
  float4 v3 = p[base + 768];
  float4 v4 = p[base + 1024];
  float4 v5 = p[base + 1280];
  float4 v6 = p[base + 1536];
  float4 v7 = p[base + 1792];
  float m0 = fminf(fminf(v0.x, v0.y), fminf(v0.z, v0.w));
  float m1 = fminf(fminf(v1.x, v1.y), fminf(v1.z, v1.w));
  float m2 = fminf(fminf(v2.x, v2.y), fminf(v2.z, v2.w));
  float m3 = fminf(fminf(v3.x, v3.y), fminf(v3.z, v3.w));
  float m4 = fminf(fminf(v4.x, v4.y), fminf(v4.z, v4.w));
  float m5 = fminf(fminf(v5.x, v5.y), fminf(v5.z, v5.w));
  float m6 = fminf(fminf(v6.x, v6.y), fminf(v6.z, v6.w));
  float m7 = fminf(fminf(v7.x, v7.y), fminf(v7.z, v7.w));
  float m = fminf(fminf(fminf(m0, m1), fminf(m2, m3)),
                  fminf(fminf(m4, m5), fminf(m6, m7)));
  for (int off = 32; off > 0; off >>= 1)
    m = fminf(m, __shfl_down(m, off, 64));
  __shared__ float wmin[4];
  int wid = threadIdx.x >> 6;
  if ((threadIdx.x & 63) == 0) wmin[wid] = m;
  __syncthreads();
  if (threadIdx.x == 0)
    pmin[row * PB + blockIdx.x] =
        fminf(fminf(wmin[0], wmin[1]), fminf(wmin[2], wmin[3]));
}

// ---- LDS-privatized accumulation; merge = plain store (partial) or atomic ----
template <int G, int S, bool ATOMIC>
__global__ __launch_bounds__(1024) void accum_kernel(
    const float* __restrict__ in, int N, float vox,
    const float* __restrict__ pmin, int PB, u64* __restrict__ Ap,
    u64* __restrict__ Bp) {
  extern __shared__ u64 lds[];
  u64* lA = lds;      // [G]  A = (ysum<<32)|xsum   (Q20)
  u64* lB = lds + G;  // [G]  B = (cnt <<32)|zsum
  __shared__ float s_m[3];
  int tid = threadIdx.x, b = blockIdx.y;
  for (int i = tid; i < G; i += 1024) { lA[i] = 0ull; lB[i] = 0ull; }

  // parallel pmin reduce: waves 0..2 each handle one coordinate
  int wid = tid >> 6, lane = tid & 63;
  if (wid < 3) {
    float v = __int_as_float(0x7F800000);
    for (int j = lane; j < PB; j += 64)
      v = fminf(v, pmin[(b * 3 + wid) * PB + j]);
    for (int off = 32; off > 0; off >>= 1)
      v = fminf(v, __shfl_down(v, off, 64));
    if (lane == 0) s_m[wid] = v;
  }
  __syncthreads();
  float m0 = s_m[0], m1 = s_m[1], m2 = s_m[2];

  int ppb = N / gridDim.x;
  const float* base = in + (size_t)b * 3 * N;
  int start = blockIdx.x * ppb;
  const float4* r0 = (const float4*)(base + start);
  const float4* r1 = (const float4*)(base + N + start);
  const float4* r2 = (const float4*)(base + 2 * N + start);
  int q4 = ppb >> 2;
  for (int i = tid; i < q4; i += 1024) {
    float4 X = r0[i], Y = r1[i], Z = r2[i];
#define PT(px, py, pz) { \
    int v0 = (int)floorf(((px) - m0) / vox); \
    int v1 = (int)floorf(((py) - m1) / vox); \
    int v2 = (int)floorf(((pz) - m2) / vox); \
    int lin = (v0 * S + v1) * S + v2; \
    u32 qx = (u32)((px) * 1048576.0f); \
    u32 qy = (u32)((py) * 1048576.0f); \
    u32 qz = (u32)((pz) * 1048576.0f); \
    atomicAdd(&lA[lin], ((u64)qy << 32) | (u64)qx); \
    atomicAdd(&lB[lin], (1ull << 32) | (u64)qz); }
    PT(X.x, Y.x, Z.x) PT(X.y, Y.y, Z.y) PT(X.z, Y.z, Z.z) PT(X.w, Y.w, Z.w)
#undef PT
  }
  __syncthreads();

  int p = ATOMIC ? 0 : blockIdx.x;
  u64* gA = Ap + ((size_t)p * 16 + b) * G;
  u64* gB = Bp + ((size_t)p * 16 + b) * G;
  for (int c = tid; c < G; c += 1024) {
    if (ATOMIC) {
      u64 Bv = lB[c];
      if (Bv) { atomicAdd(&gA[c], lA[c]); atomicAdd(&gB[c], Bv); }
    } else {
      gA[c] = lA[c];
      gB[c] = lB[c];
    }
  }
}

// ---- sum P partials -> per-cell float4 {mx,my,mz,cnt} + per-block occ count ----
__global__ void reduce_kernel(int G, int P, const u64* __restrict__ Ap,
                              const u64* __restrict__ Bp,
                              float4* __restrict__ vox4,
                              u32* __restrict__ bcnt) {
  int blk = blockIdx.x, b = blockIdx.y, tid = threadIdx.x;
  int cell = blk * 256 + tid;
  u64 A = 0ull, Bv = 0ull;
  if (cell < G) {
    for (int p = 0; p < P; ++p) {
      size_t o = ((size_t)p * 16 + b) * G + cell;
      A += Ap[o];
      Bv += Bp[o];
    }
  }
  u32 cnt = (u32)(Bv >> 32);
  if (cell < G) {
    float4 o4 = make_float4(0.f, 0.f, 0.f, 0.f);
    if (cnt) {
      double inv = 1.0 / (1048576.0 * (double)cnt);
      o4.x = (float)((double)(u32)A * inv);
      o4.y = (float)((double)(u32)(A >> 32) * inv);
      o4.z = (float)((double)(u32)Bv * inv);
      o4.w = (float)cnt;
    }
    vox4[(size_t)b * G + cell] = o4;
  }
  u64 mask = __ballot(cnt > 0u);
  __shared__ u32 wtot[4];
  if ((tid & 63) == 0) wtot[tid >> 6] = (u32)__popcll(mask);
  __syncthreads();
  if (tid == 0)
    bcnt[b * gridDim.x + blk] = wtot[0] + wtot[1] + wtot[2] + wtot[3];
}

// ---- parallel compaction: per-block base from bcnt, ballot-compact ----
__global__ void compact_b_kernel(int G, const float4* __restrict__ vox4,
                                 const u32* __restrict__ bcnt,
                                 float4* __restrict__ means4,
                                 u32* __restrict__ numvox) {
  int blk = blockIdx.x, nb = gridDim.x, b = blockIdx.y, tid = threadIdx.x;
  int lane = tid & 63, wid = tid >> 6;
  int cell = blk * 256 + tid;
  float4 v = make_float4(0.f, 0.f, 0.f, 0.f);
  bool occ = false;
  if (cell < G) {
    v = vox4[(size_t)b * G + cell];
    occ = v.w > 0.f;
  }
  u64 mask = __ballot(occ);
  u32 prefix = (u32)__popcll(mask & ((1ull << lane) - 1ull));
  __shared__ u32 wb[4];
  if (lane == 0) wb[wid] = (u32)__popcll(mask);
  __syncthreads();
  if (tid == 0) {
    u32 base = 0;
    for (int j = 0; j < blk; ++j) base += bcnt[b * nb + j];
    u32 s = base;
    for (int w = 0; w < 4; ++w) { u32 t = wb[w]; wb[w] = s; s += t; }
    if (blk == nb - 1) numvox[b] = s;
  }
  __syncthreads();
  if (occ) means4[(size_t)b * G + wb[wid] + prefix] = v;
}

// ---- fused reduce+compact for G <= 1024 (layer 2 big path) ----
template <int G>
__global__ __launch_bounds__(1024) void redcomp_kernel(
    int P, const u64* __restrict__ Ap, const u64* __restrict__ Bp,
    float4* __restrict__ means4, u32* __restrict__ numvox) {
  int b = blockIdx.x, tid = threadIdx.x, wid = tid >> 6, lane = tid & 63;
  u64 A = 0ull, Bv = 0ull;
  if (tid < G) {
    for (int p = 0; p < P; ++p) {
      size_t o = ((size_t)p * 16 + b) * G + tid;
      A += Ap[o];
      Bv += Bp[o];
    }
  }
  u32 cnt = (u32)(Bv >> 32);
  float4 v = make_float4(0.f, 0.f, 0.f, 0.f);
  if (cnt) {
    double inv = 1.0 / (1048576.0 * (double)cnt);
    v.x = (float)((double)(u32)A * inv);
    v.y = (float)((double)(u32)(A >> 32) * inv);
    v.z = (float)((double)(u32)Bv * inv);
  }
  bool occ = cnt > 0u;
  u64 mask = __ballot(occ);
  u32 prefix = (u32)__popcll(mask & ((1ull << lane) - 1ull));
  __shared__ u32 wtot[16], wbase[16];
  if (lane == 0) wtot[wid] = (u32)__popcll(mask);
  __syncthreads();
  if (tid == 0) {
    u32 s = 0;
    for (int w = 0; w < 16; ++w) { wbase[w] = s; s += wtot[w]; }
    numvox[b] = s;
  }
  __syncthreads();
  if (occ) means4[(size_t)b * G + wbase[wid] + prefix] = v;
}

// ---- serial-scan compaction (small/atomic path only) ----
__global__ __launch_bounds__(1024) void compact_kernel(
    int G, const u64* __restrict__ Ac, const u64* __restrict__ Bc,
    float4* __restrict__ means4, u32* __restrict__ numvox) {
  int b = blockIdx.x, tid = threadIdx.x, wid = tid >> 6, lane = tid & 63;
  __shared__ u32 wtot[16], wbase[16];
  __shared__ u32 gbase;
  if (tid == 0) gbase = 0u;
  __syncthreads();
  for (int t0 = 0; t0 < G; t0 += 1024) {
    int cell = t0 + tid;
    float4 v = make_float4(0.f, 0.f, 0.f, 0.f);
    u32 cnt = 0u;
    if (cell < G) {
      u64 A = Ac[(size_t)b * G + cell], Bv = Bc[(size_t)b * G + cell];
      cnt = (u32)(Bv >> 32);
      if (cnt) {
        double inv = 1.0 / (1048576.0 * (double)cnt);
        v.x = (float)((double)(u32)A * inv);
        v.y = (float)((double)(u32)(A >> 32) * inv);
        v.z = (float)((double)(u32)Bv * inv);
      }
    }
    bool occ = cnt > 0u;
    u64 mask = __ballot(occ);
    u32 prefix = (u32)__popcll(mask & ((1ull << lane) - 1ull));
    if (lane == 0) wtot[wid] = (u32)__popcll(mask);
    __syncthreads();
    if (tid == 0) {
      u32 s = gbase;
      for (int w = 0; w < 16; ++w) { wbase[w] = s; s += wtot[w]; }
      gbase = s;
    }
    __syncthreads();
    if (occ) means4[(size_t)b * G + wbase[wid] + prefix] = v;
    __syncthreads();
  }
  if (tid == 0) numvox[b] = gbase;
}

// ---- threefry sample: 4 outputs/thread; optional fused next-layer
//      partial-min via PLAIN per-block stores (no atomics) ----
template <bool DOMIN>
__global__ void sample_kernel(int L, int G, const float4* __restrict__ means4,
                              const u32* __restrict__ numvox, KeyArr keys,
                              float* __restrict__ out,
                              float* __restrict__ pmin) {
  int t = blockIdx.x * 256 + threadIdx.x;
  int b = blockIdx.y;
  int l0 = t * 4;  // L multiple of 1024 -> no tail guard
  u32 nv = numvox[b];
  float fnv = (float)nv;
  int nvm1 = (int)nv - 1;
  uint32_t K0 = keys.k0[b], K1 = keys.k1[b];
  float4 m[4];
#pragma unroll
  for (int j = 0; j < 4; ++j) {
    uint32_t w0, w1;
    tf2x32(K0, K1, 0u, (uint32_t)(l0 + j), w0, w1);
    uint32_t bits = w0 ^ w1;  // partitionable fold
    float u = __uint_as_float((bits >> 9) | 0x3F800000u) - 1.0f;
    int idx = (int)(u * fnv);  // f32 RN mul, trunc
    if (idx > nvm1) idx = nvm1;
    m[j] = means4[(size_t)b * G + idx];
  }
  *(float4*)(out + ((size_t)b * 3 + 0) * L + l0) =
      make_float4(m[0].x, m[1].x, m[2].x, m[3].x);
  *(float4*)(out + ((size_t)b * 3 + 1) * L + l0) =
      make_float4(m[0].y, m[1].y, m[2].y, m[3].y);
  *(float4*)(out + ((size_t)b * 3 + 2) * L + l0) =
      make_float4(m[0].z, m[1].z, m[2].z, m[3].z);
  if (DOMIN) {
    float ax = fminf(fminf(m[0].x, m[1].x), fminf(m[2].x, m[3].x));
    float ay = fminf(fminf(m[0].y, m[1].y), fminf(m[2].y, m[3].y));
    float az = fminf(fminf(m[0].z, m[1].z), fminf(m[2].z, m[3].z));
    for (int off = 32; off > 0; off >>= 1) {
      ax = fminf(ax, __shfl_down(ax, off, 64));
      ay = fminf(ay, __shfl_down(ay, off, 64));
      az = fminf(az, __shfl_down(az, off, 64));
    }
    __shared__ float wm[4][3];
    int wid = threadIdx.x >> 6;
    if ((threadIdx.x & 63) == 0) {
      wm[wid][0] = ax; wm[wid][1] = ay; wm[wid][2] = az;
    }
    __syncthreads();
    if (threadIdx.x == 0) {
      int PB = gridDim.x;
      pmin[(b * 3 + 0) * PB + blockIdx.x] =
          fminf(fminf(wm[0][0], wm[1][0]), fminf(wm[2][0], wm[3][0]));
      pmin[(b * 3 + 1) * PB + blockIdx.x] =
          fminf(fminf(wm[0][1], wm[1][1]), fminf(wm[2][1], wm[3][1]));
      pmin[(b * 3 + 2) * PB + blockIdx.x] =
          fminf(fminf(wm[0][2], wm[1][2]), fminf(wm[2][2], wm[3][2]));
    }
  }
}

extern "C" void kernel_launch(void* const* d_in, const int* in_sizes, int n_in,
                              void* d_out, int out_size, void* d_ws,
                              size_t ws_size, hipStream_t stream) {
  const float* x = (const float*)d_in[0];
  float* out = (float*)d_out;

  // ---- JAX key derivation (threefry partitionable split) ----
  uint32_t k1a, k1b, k2a, k2b;
  tf2x32(0u, 42u, 0u, 0u, k1a, k1b);
  tf2x32(0u, 42u, 0u, 1u, k2a, k2b);
  KeyArr keys1, keys2;
  for (int b = 0; b < 16; ++b) {
    tf2x32(k1a, k1b, 0u, (uint32_t)b, keys1.k0[b], keys1.k1[b]);
    tf2x32(k2a, k2b, 0u, (uint32_t)b, keys2.k0[b], keys2.k1[b]);
  }

  const int N1 = 262144, L1 = 131072, L2 = 65536, G1 = 8000, G2 = 1000;
  const int PB1 = 32, PB2 = 128, NB1 = 32;  // PB2 = L1/1024 sample1 blocks
  const size_t slice1 = (size_t)16 * G1, slice2 = (size_t)16 * G2;

  const size_t tailBytes =
      (48 * PB1 + 48 * PB2 + 16 * NB1 + 32) * 4 + 256;
  const size_t bigNeed =
      2ull * 16 * slice1 * 8 + 2ull * slice1 * 16 + tailBytes;
  bool big = ws_size >= bigNeed;

  uint8_t* w = (uint8_t*)d_ws;
  u64 *Ap, *Bp;
  float4 *vox4 = nullptr, *means4;
  uint8_t* tail;
  if (big) {
    Ap = (u64*)w;
    Bp = Ap + 16 * slice1;
    vox4 = (float4*)(Bp + 16 * slice1);
    means4 = vox4 + slice1;
    tail = (uint8_t*)(means4 + slice1);
  } else {
    Ap = (u64*)w;  // [slice1 | slice2] atomic cells
    Bp = Ap + (slice1 + slice2);
    means4 = (float4*)(Bp + (slice1 + slice2));
    tail = (uint8_t*)(means4 + slice1);
  }
  float* pmin1 = (float*)tail;             // 48*PB1
  float* pmin2 = pmin1 + 48 * PB1;         // 48*PB2
  u32* bcnt = (u32*)(pmin2 + 48 * PB2);    // 16*NB1
  u32* numvox = bcnt + 16 * NB1;           // 32

  if (!big) {
    init_kernel<<<dim3(64), dim3(256), 0, stream>>>(
        Ap, Bp, (int)(slice1 + slice2));
  }

  // ---- layer 1: vox=0.05, S=20 (v<=19 proven), G=8000 ----
  min_kernel<<<dim3(PB1, 48), dim3(256), 0, stream>>>(x, N1 / 4, pmin1);
  if (big) {
    accum_kernel<G1, 20, false>
        <<<dim3(16, 16), dim3(1024), 2 * G1 * 8, stream>>>(x, N1, 0.05f,
                                                           pmin1, PB1, Ap, Bp);
    reduce_kernel<<<dim3(NB1, 16), dim3(256), 0, stream>>>(G1, 16, Ap, Bp,
                                                           vox4, bcnt);
    compact_b_kernel<<<dim3(NB1, 16), dim3(256), 0, stream>>>(
        G1, vox4, bcnt, means4, numvox);
  } else {
    accum_kernel<G1, 20, true>
        <<<dim3(8, 16), dim3(1024), 2 * G1 * 8, stream>>>(x, N1, 0.05f, pmin1,
                                                          PB1, Ap, Bp);
    compact_kernel<<<dim3(16), dim3(1024), 0, stream>>>(G1, Ap, Bp, means4,
                                                        numvox);
  }
  // sample layer 1 + fused layer-2 partial min (plain stores)
  sample_kernel<true><<<dim3(L1 / 1024, 16), dim3(256), 0, stream>>>(
      L1, G1, means4, numvox, keys1, out, pmin2);

  // ---- layer 2: input = out1, vox=0.1, S=10 (v<=9), G=1000 ----
  float* out2 = out + (size_t)48 * L1;
  if (big) {
    accum_kernel<G2, 10, false>
        <<<dim3(16, 16), dim3(1024), 2 * G2 * 8, stream>>>(
            out, L1, 0.1f, pmin2, PB2, Ap, Bp);
    redcomp_kernel<G2><<<dim3(16), dim3(1024), 0, stream>>>(
        16, Ap, Bp, means4, numvox + 16);
  } else {
    accum_kernel<G2, 10, true>
        <<<dim3(8, 16), dim3(1024), 2 * G2 * 8, stream>>>(
            out, L1, 0.1f, pmin2, PB2, Ap + slice1, Bp + slice1);
    compact_kernel<<<dim3(16), dim3(1024), 0, stream>>>(
        G2, Ap + slice1, Bp + slice1, means4, numvox + 16);
  }
  sample_kernel<false><<<dim3(L2 / 1024, 16), dim3(256), 0, stream>>>(
      L2, G2, means4, numvox + 16, keys2, out2, nullptr);
}